// Round 2
// baseline (889.588 us; speedup 1.0000x reference)
//
#include <hip/hip_runtime.h>
#include <hip/hip_bf16.h>

// ---------------------------------------------------------------------------
// HeteroGCN: 2-layer, 2-relation GCN on N=100k nodes, E=1M edges/relation,
// all feature dims = 64.
//
// Per conv (PyG GCNConv w/ self-loops):
//   deg[d] = 1 + #incoming edges, dinv = rsqrt(deg)
//   t      = dinv * (X @ W)                    (row-scaled dense matmul)
//   out[d] = dinv[d] * (t[d] + sum_{(s,d)} t[s]) + b
//
// Strategy: build dst-CSR per relation once per launch (count + scan + fill),
// then each conv = fused GEMM (both relations) + fused gather (both
// relations, wave-per-node, lane-per-feature). No atomics in hot path.
// ---------------------------------------------------------------------------

__global__ void count_dst(const int* __restrict__ ei, int* __restrict__ cnt, int E) {
    int i = blockIdx.x * blockDim.x + threadIdx.x;
    if (i < E) atomicAdd(&cnt[ei[E + i]], 1);
}

__global__ void calc_dinv(const int* __restrict__ cnt, float* __restrict__ dinv, int n) {
    int i = blockIdx.x * blockDim.x + threadIdx.x;
    if (i < n) dinv[i] = rsqrtf((float)(cnt[i] + 1));
}

// pass 1: per-block (1024 elems) exclusive scan, block totals to bsum
__global__ void scan_blocks(const int* __restrict__ cnt, int* __restrict__ off,
                            int* __restrict__ bsum, int n) {
    __shared__ int sh[256];
    int tid = threadIdx.x;
    int base = blockIdx.x * 1024 + tid * 4;
    int c0 = (base + 0 < n) ? cnt[base + 0] : 0;
    int c1 = (base + 1 < n) ? cnt[base + 1] : 0;
    int c2 = (base + 2 < n) ? cnt[base + 2] : 0;
    int c3 = (base + 3 < n) ? cnt[base + 3] : 0;
    int tsum = c0 + c1 + c2 + c3;
    sh[tid] = tsum;
    __syncthreads();
    for (int ofs = 1; ofs < 256; ofs <<= 1) {
        int v = 0;
        if (tid >= ofs) v = sh[tid - ofs];
        __syncthreads();
        if (tid >= ofs) sh[tid] += v;
        __syncthreads();
    }
    int excl = sh[tid] - tsum;
    int run = excl;
    if (base + 0 < n) off[base + 0] = run; run += c0;
    if (base + 1 < n) off[base + 1] = run; run += c1;
    if (base + 2 < n) off[base + 2] = run; run += c2;
    if (base + 3 < n) off[base + 3] = run;
    if (tid == 255) bsum[blockIdx.x] = sh[255];
}

// pass 2: exclusive scan of block sums (nb ~ 98, trivial serial)
__global__ void scan_bsum(int* __restrict__ bsum, int nb) {
    if (blockIdx.x == 0 && threadIdx.x == 0) {
        int run = 0;
        for (int i = 0; i < nb; ++i) { int t = bsum[i]; bsum[i] = run; run += t; }
    }
}

// pass 3: add block offsets, set off[n] = total
__global__ void scan_add(int* __restrict__ off, const int* __restrict__ bsum,
                         int n, int total) {
    int i = blockIdx.x * blockDim.x + threadIdx.x;
    if (i < n) off[i] += bsum[i >> 10];
    if (i == 0) off[n] = total;
}

__global__ void copy_int(int* __restrict__ dst, const int* __restrict__ src, int n) {
    int i = blockIdx.x * blockDim.x + threadIdx.x;
    if (i < n) dst[i] = src[i];
}

__global__ void fill_csr(const int* __restrict__ ei, int* __restrict__ cur,
                         int* __restrict__ srclist, int E) {
    int i = blockIdx.x * blockDim.x + threadIdx.x;
    if (i < E) {
        int s = ei[i];
        int d = ei[E + i];
        int p = atomicAdd(&cur[d], 1);
        srclist[p] = s;
    }
}

// Fused dual-relation GEMM: ta = da .* (X@Wa), tb = db .* (X@Wb).
// One wave per row; lane j owns output column j; W tiles in LDS.
__global__ __launch_bounds__(256) void gemm2(
        const float* __restrict__ X,
        const float* __restrict__ Wa, const float* __restrict__ Wb,
        const float* __restrict__ da, const float* __restrict__ db,
        float* __restrict__ ta, float* __restrict__ tb, int n) {
    __shared__ float wa[64 * 64];
    __shared__ float wb[64 * 64];
    for (int i = threadIdx.x; i < 64 * 64; i += 256) { wa[i] = Wa[i]; wb[i] = Wb[i]; }
    __syncthreads();
    int wave = threadIdx.x >> 6;
    int lane = threadIdx.x & 63;
    for (int r = blockIdx.x * 4 + wave; r < n; r += gridDim.x * 4) {
        float xv = X[(size_t)r * 64 + lane];
        float a1 = 0.f, a2 = 0.f;
        #pragma unroll
        for (int k = 0; k < 64; ++k) {
            float xk = __shfl(xv, k, 64);
            a1 = fmaf(xk, wa[k * 64 + lane], a1);
            a2 = fmaf(xk, wb[k * 64 + lane], a2);
        }
        float s1 = da[r], s2 = db[r];
        ta[(size_t)r * 64 + lane] = a1 * s1;
        tb[(size_t)r * 64 + lane] = a2 * s2;
    }
}

// Fused dual-relation gather: out[d] = opt_relu( da[d]*(ta[d]+sum ta[s])
//                                              + db[d]*(tb[d]+sum tb[s])
//                                              + bia + bib )
template <int RELU>
__global__ __launch_bounds__(256) void gather2(
        const float* __restrict__ ta, const float* __restrict__ tb,
        const int* __restrict__ offa, const int* __restrict__ srca,
        const int* __restrict__ offb, const int* __restrict__ srcb,
        const float* __restrict__ da, const float* __restrict__ db,
        const float* __restrict__ bia, const float* __restrict__ bib,
        float* __restrict__ out, int n) {
    int node = blockIdx.x * 4 + (threadIdx.x >> 6);
    if (node >= n) return;
    int lane = threadIdx.x & 63;

    float acc1 = ta[(size_t)node * 64 + lane];   // self-loop term
    int e0 = offa[node], e1 = offa[node + 1];
    for (int e = e0; e < e1; ++e) {
        int s = srca[e];
        acc1 += ta[(size_t)s * 64 + lane];
    }
    float acc2 = tb[(size_t)node * 64 + lane];
    int f0 = offb[node], f1 = offb[node + 1];
    for (int e = f0; e < f1; ++e) {
        int s = srcb[e];
        acc2 += tb[(size_t)s * 64 + lane];
    }
    float v = acc1 * da[node] + acc2 * db[node] + bia[lane] + bib[lane];
    if (RELU) v = fmaxf(v, 0.f);
    out[(size_t)node * 64 + lane] = v;
}

extern "C" void kernel_launch(void* const* d_in, const int* in_sizes, int n_in,
                              void* d_out, int out_size, void* d_ws, size_t ws_size,
                              hipStream_t stream) {
    const float* x   = (const float*)d_in[0];
    const int*   ei1 = (const int*)d_in[1];
    const int*   ei2 = (const int*)d_in[2];
    const float* W1a = (const float*)d_in[3];
    const float* b1a = (const float*)d_in[4];
    const float* W1b = (const float*)d_in[5];
    const float* b1b = (const float*)d_in[6];
    const float* W2a = (const float*)d_in[7];
    const float* b2a = (const float*)d_in[8];
    const float* W2b = (const float*)d_in[9];
    const float* b2b = (const float*)d_in[10];

    const int N = in_sizes[0] / 64;
    const int E = in_sizes[1] / 2;
    float* out = (float*)d_out;

    // workspace carve-out
    char* w = (char*)d_ws;
    auto alloc = [&](size_t bytes) {
        char* p = w;
        w += (bytes + 255) & ~(size_t)255;
        return p;
    };
    float* t1    = (float*)alloc((size_t)N * 64 * sizeof(float));
    float* t2    = (float*)alloc((size_t)N * 64 * sizeof(float));
    float* dinv1 = (float*)alloc((size_t)N * sizeof(float));
    float* dinv2 = (float*)alloc((size_t)N * sizeof(float));
    int*   cnt1  = (int*)alloc((size_t)N * sizeof(int));
    int*   cnt2  = (int*)alloc((size_t)N * sizeof(int));
    int*   off1  = (int*)alloc((size_t)(N + 1) * sizeof(int));
    int*   off2  = (int*)alloc((size_t)(N + 1) * sizeof(int));
    int*   cur1  = (int*)alloc((size_t)N * sizeof(int));
    int*   cur2  = (int*)alloc((size_t)N * sizeof(int));
    int*   src1  = (int*)alloc((size_t)E * sizeof(int));
    int*   src2  = (int*)alloc((size_t)E * sizeof(int));
    const int nb = (N + 1023) / 1024;
    int*   bsum1 = (int*)alloc((size_t)nb * sizeof(int));
    int*   bsum2 = (int*)alloc((size_t)nb * sizeof(int));

    const int gE = (E + 255) / 256;
    const int gN = (N + 255) / 256;

    // ---- degree + CSR build (identical work every call; capture-safe) ----
    hipMemsetAsync(cnt1, 0, (size_t)N * sizeof(int), stream);
    hipMemsetAsync(cnt2, 0, (size_t)N * sizeof(int), stream);
    count_dst<<<gE, 256, 0, stream>>>(ei1, cnt1, E);
    count_dst<<<gE, 256, 0, stream>>>(ei2, cnt2, E);
    calc_dinv<<<gN, 256, 0, stream>>>(cnt1, dinv1, N);
    calc_dinv<<<gN, 256, 0, stream>>>(cnt2, dinv2, N);
    scan_blocks<<<nb, 256, 0, stream>>>(cnt1, off1, bsum1, N);
    scan_blocks<<<nb, 256, 0, stream>>>(cnt2, off2, bsum2, N);
    scan_bsum<<<1, 1, 0, stream>>>(bsum1, nb);
    scan_bsum<<<1, 1, 0, stream>>>(bsum2, nb);
    scan_add<<<gN, 256, 0, stream>>>(off1, bsum1, N, E);
    scan_add<<<gN, 256, 0, stream>>>(off2, bsum2, N, E);
    copy_int<<<gN, 256, 0, stream>>>(cur1, off1, N);
    copy_int<<<gN, 256, 0, stream>>>(cur2, off2, N);
    fill_csr<<<gE, 256, 0, stream>>>(ei1, cur1, src1, E);
    fill_csr<<<gE, 256, 0, stream>>>(ei2, cur2, src2, E);

    const int gNode = (N + 3) / 4;

    // ---- layer 1: h = relu(conv_r1(x) + conv_r2(x)); h lives in d_out ----
    gemm2<<<1024, 256, 0, stream>>>(x, W1a, W1b, dinv1, dinv2, t1, t2, N);
    gather2<1><<<gNode, 256, 0, stream>>>(t1, t2, off1, src1, off2, src2,
                                          dinv1, dinv2, b1a, b1b, out, N);

    // ---- layer 2: out = conv_r1(h) + conv_r2(h) ----
    gemm2<<<1024, 256, 0, stream>>>(out, W2a, W2b, dinv1, dinv2, t1, t2, N);
    gather2<0><<<gNode, 256, 0, stream>>>(t1, t2, off1, src1, off2, src2,
                                          dinv1, dinv2, b2a, b2b, out, N);
}

// Round 3
// 769.215 us; speedup vs baseline: 1.1565x; 1.1565x over previous
//
#include <hip/hip_runtime.h>
#include <hip/hip_bf16.h>

// ---------------------------------------------------------------------------
// HeteroGCN: 2-layer, 2-relation GCN. N=100k, E=1M/relation, D=64.
//
// out[d] = dinv[d]*(t[d] + sum_{(s,d)} t[s]) + b,  t = dinv .* (X@W)
//
// R2 analysis: gather was latency*MLP-bound (1.59 TB/s, VALUBusy 14.5%).
// R3: merged-relation CSR (single src list, relation tag folded into row
// index of a single 2N-row t table) + masked 8-wide unrolled gather loop
// -> 8 row loads in flight per wave. CSR-build fused to 8 dispatches.
// ---------------------------------------------------------------------------

#define NF 64  // feature dim

// count incoming edges for both relations: cnt[0..N) = rel1, cnt[N..2N) = rel2
__global__ void count2(const int* __restrict__ ei1, const int* __restrict__ ei2,
                       int* __restrict__ cnt, int N, int E) {
    int i = blockIdx.x * blockDim.x + threadIdx.x;
    if (i < 2 * E) {
        int d = (i < E) ? ei1[E + i] : ei2[E + (i - E)];
        int base = (i < E) ? 0 : N;
        atomicAdd(&cnt[base + d], 1);
    }
}

// dinv per relation + combined count for the merged scan
__global__ void dinv_sum(const int* __restrict__ cnt, float* __restrict__ dinv1,
                         float* __restrict__ dinv2, int* __restrict__ csum, int n) {
    int i = blockIdx.x * blockDim.x + threadIdx.x;
    if (i < n) {
        int c1 = cnt[i], c2 = cnt[n + i];
        dinv1[i] = rsqrtf((float)(c1 + 1));
        dinv2[i] = rsqrtf((float)(c2 + 1));
        csum[i] = c1 + c2;
    }
}

// pass 1: per-block (1024 elems) exclusive scan, block totals to bsum
__global__ void scan_blocks(const int* __restrict__ cnt, int* __restrict__ off,
                            int* __restrict__ bsum, int n) {
    __shared__ int sh[256];
    int tid = threadIdx.x;
    int base = blockIdx.x * 1024 + tid * 4;
    int c0 = (base + 0 < n) ? cnt[base + 0] : 0;
    int c1 = (base + 1 < n) ? cnt[base + 1] : 0;
    int c2 = (base + 2 < n) ? cnt[base + 2] : 0;
    int c3 = (base + 3 < n) ? cnt[base + 3] : 0;
    int tsum = c0 + c1 + c2 + c3;
    sh[tid] = tsum;
    __syncthreads();
    for (int ofs = 1; ofs < 256; ofs <<= 1) {
        int v = 0;
        if (tid >= ofs) v = sh[tid - ofs];
        __syncthreads();
        if (tid >= ofs) sh[tid] += v;
        __syncthreads();
    }
    int excl = sh[tid] - tsum;
    int run = excl;
    if (base + 0 < n) off[base + 0] = run; run += c0;
    if (base + 1 < n) off[base + 1] = run; run += c1;
    if (base + 2 < n) off[base + 2] = run; run += c2;
    if (base + 3 < n) off[base + 3] = run;
    if (tid == 255) bsum[blockIdx.x] = sh[255];
}

// pass 2: parallel exclusive scan of block sums (nb <= 256)
__global__ void scan_bsum(int* __restrict__ bsum, int nb) {
    __shared__ int sh[256];
    int tid = threadIdx.x;
    int v = (tid < nb) ? bsum[tid] : 0;
    sh[tid] = v;
    __syncthreads();
    for (int ofs = 1; ofs < 256; ofs <<= 1) {
        int u = (tid >= ofs) ? sh[tid - ofs] : 0;
        __syncthreads();
        sh[tid] += u;
        __syncthreads();
    }
    if (tid < nb) bsum[tid] = sh[tid] - v;   // exclusive
}

// pass 3: add block offsets, set off[n] = total
__global__ void scan_add(int* __restrict__ off, const int* __restrict__ bsum,
                         int n, int total) {
    int i = blockIdx.x * blockDim.x + threadIdx.x;
    if (i < n) off[i] += bsum[i >> 10];
    if (i == 0) off[n] = total;
}

__global__ void copy_int(int* __restrict__ dst, const int* __restrict__ src, int n) {
    int i = blockIdx.x * blockDim.x + threadIdx.x;
    if (i < n) dst[i] = src[i];
}

// fill merged CSR: rel-2 sources stored as s+N (row index into 2N-row t table)
__global__ void fill2(const int* __restrict__ ei1, const int* __restrict__ ei2,
                      int* __restrict__ cur, int* __restrict__ msrc, int N, int E) {
    int i = blockIdx.x * blockDim.x + threadIdx.x;
    if (i < 2 * E) {
        int s, d;
        if (i < E) { s = ei1[i];     d = ei1[E + i]; }
        else       { s = ei2[i - E] + N; d = ei2[E + (i - E)]; }
        int p = atomicAdd(&cur[d], 1);
        msrc[p] = s;
    }
}

// Fused dual-relation GEMM: t[r] = da .* (X@Wa), t[N+r] = db .* (X@Wb)
__global__ __launch_bounds__(256) void gemm2(
        const float* __restrict__ X,
        const float* __restrict__ Wa, const float* __restrict__ Wb,
        const float* __restrict__ da, const float* __restrict__ db,
        float* __restrict__ t, int n) {
    __shared__ float wa[NF * NF];
    __shared__ float wb[NF * NF];
    for (int i = threadIdx.x; i < NF * NF; i += 256) { wa[i] = Wa[i]; wb[i] = Wb[i]; }
    __syncthreads();
    int wave = threadIdx.x >> 6;
    int lane = threadIdx.x & 63;
    for (int r = blockIdx.x * 4 + wave; r < n; r += gridDim.x * 4) {
        float xv = X[(size_t)r * NF + lane];
        float a1 = 0.f, a2 = 0.f;
        #pragma unroll
        for (int k = 0; k < NF; ++k) {
            float xk = __shfl(xv, k, 64);
            a1 = fmaf(xk, wa[k * NF + lane], a1);
            a2 = fmaf(xk, wb[k * NF + lane], a2);
        }
        t[(size_t)r * NF + lane]            = a1 * da[r];
        t[(size_t)(n + r) * NF + lane]      = a2 * db[r];
    }
}

// Merged gather: one wave per node, lane per feature, masked 8-wide unroll.
// t is [2N][64]; msrc entries < N are rel-1, >= N are rel-2.
template <int RELU>
__global__ __launch_bounds__(256) void gather2(
        const float* __restrict__ t,
        const int* __restrict__ moff, const int* __restrict__ msrc,
        const float* __restrict__ da, const float* __restrict__ db,
        const float* __restrict__ bia, const float* __restrict__ bib,
        float* __restrict__ out, int n) {
    int node = blockIdx.x * 4 + (threadIdx.x >> 6);
    if (node >= n) return;
    int lane = threadIdx.x & 63;

    // self-loop terms (issue early)
    float self1 = t[(size_t)node * NF + lane];
    float self2 = t[(size_t)(n + node) * NF + lane];

    float acc1 = 0.f, acc2 = 0.f;
    int e0 = moff[node], e1 = moff[node + 1];
    for (int e = e0; e < e1; e += 8) {
        #pragma unroll
        for (int j = 0; j < 8; ++j) {
            int ee = e + j;
            bool v = ee < e1;
            int idx = v ? msrc[ee] : node;          // msrc padded; safe load
            float r = t[(size_t)idx * NF + lane];   // node row is L1-hot
            float rv = v ? r : 0.f;
            bool isB = idx >= n;
            acc1 += isB ? 0.f : rv;
            acc2 += isB ? rv : 0.f;
        }
    }
    float v = (acc1 + self1) * da[node] + (acc2 + self2) * db[node]
            + bia[lane] + bib[lane];
    if (RELU) v = fmaxf(v, 0.f);
    out[(size_t)node * NF + lane] = v;
}

extern "C" void kernel_launch(void* const* d_in, const int* in_sizes, int n_in,
                              void* d_out, int out_size, void* d_ws, size_t ws_size,
                              hipStream_t stream) {
    const float* x   = (const float*)d_in[0];
    const int*   ei1 = (const int*)d_in[1];
    const int*   ei2 = (const int*)d_in[2];
    const float* W1a = (const float*)d_in[3];
    const float* b1a = (const float*)d_in[4];
    const float* W1b = (const float*)d_in[5];
    const float* b1b = (const float*)d_in[6];
    const float* W2a = (const float*)d_in[7];
    const float* b2a = (const float*)d_in[8];
    const float* W2b = (const float*)d_in[9];
    const float* b2b = (const float*)d_in[10];

    const int N = in_sizes[0] / NF;
    const int E = in_sizes[1] / 2;
    float* out = (float*)d_out;

    // workspace carve-out
    char* w = (char*)d_ws;
    auto alloc = [&](size_t bytes) {
        char* p = w;
        w += (bytes + 255) & ~(size_t)255;
        return p;
    };
    float* t     = (float*)alloc((size_t)2 * N * NF * sizeof(float)); // [2N][64]
    float* dinv1 = (float*)alloc((size_t)N * sizeof(float));
    float* dinv2 = (float*)alloc((size_t)N * sizeof(float));
    int*   cnt   = (int*)alloc((size_t)2 * N * sizeof(int));          // rel1|rel2
    int*   csum  = (int*)alloc((size_t)N * sizeof(int));
    int*   moff  = (int*)alloc((size_t)(N + 1) * sizeof(int));
    int*   cur   = (int*)alloc((size_t)N * sizeof(int));
    int*   msrc  = (int*)alloc(((size_t)2 * E + 8) * sizeof(int));    // +8 pad
    const int nb = (N + 1023) / 1024;
    int*   bsum  = (int*)alloc((size_t)nb * sizeof(int));

    const int g2E = (2 * E + 255) / 256;
    const int gN  = (N + 255) / 256;

    // ---- degree + merged CSR build ----
    hipMemsetAsync(cnt, 0, (size_t)2 * N * sizeof(int), stream);
    count2<<<g2E, 256, 0, stream>>>(ei1, ei2, cnt, N, E);
    dinv_sum<<<gN, 256, 0, stream>>>(cnt, dinv1, dinv2, csum, N);
    scan_blocks<<<nb, 256, 0, stream>>>(csum, moff, bsum, N);
    scan_bsum<<<1, 256, 0, stream>>>(bsum, nb);
    scan_add<<<gN, 256, 0, stream>>>(moff, bsum, N, 2 * E);
    copy_int<<<gN, 256, 0, stream>>>(cur, moff, N);
    fill2<<<g2E, 256, 0, stream>>>(ei1, ei2, cur, msrc, N, E);

    const int gNode = (N + 3) / 4;

    // ---- layer 1: h = relu(conv_r1(x) + conv_r2(x)); h lives in d_out ----
    gemm2<<<1024, 256, 0, stream>>>(x, W1a, W1b, dinv1, dinv2, t, N);
    gather2<1><<<gNode, 256, 0, stream>>>(t, moff, msrc, dinv1, dinv2,
                                          b1a, b1b, out, N);

    // ---- layer 2: out = conv_r1(h) + conv_r2(h) ----
    gemm2<<<1024, 256, 0, stream>>>(out, W2a, W2b, dinv1, dinv2, t, N);
    gather2<0><<<gNode, 256, 0, stream>>>(t, moff, msrc, dinv1, dinv2,
                                          b2a, b2b, out, N);
}